// Round 6
// baseline (515.331 us; speedup 1.0000x reference)
//
#include <hip/hip_runtime.h>
#include <math.h>

// GRUDetector: B=1024, T=512, F=64, H=128, gates (r,z,n), + MLP head (H->32->1).
// R6: R5 (425us) was LDS-BW-bound: 24 ds_read_b128/wave/step = 196KB/step ~=
// 2310 cyc/step at 85 B/cyc = measured 2320. Fix: hoist the 18 weight f16x8
// fragments into registers ONCE, pinned with asm volatile("+v") so the
// compiler cannot sink/rematerialize them (R2-R4 lesson), budget pinned via
// amdgpu_waves_per_eu(2,2) (256 VGPR >> ~170 demand). Loop LDS traffic drops
// 4x (6 u-frags/wave/step). Also: gate MFMA chains split 6->3 deep (2 accs),
// x prefetch deepened to lookahead-3 (issue x(t+3) at t; LDS-write x(t+1)).
// Skeleton, layouts, gate math identical to R5 (proven, absmax 9.8e-4).

#define Bsz  1024
#define Tlen 512
#define Fdim 64
#define Hdim 128
#define Gdim 384
#define NB   16
#define NTHR 512
#define NBLK (Bsz / NB)   // 64

typedef __attribute__((ext_vector_type(8))) _Float16 f16x8;
typedef __attribute__((ext_vector_type(4))) _Float16 f16x4;
typedef __attribute__((ext_vector_type(2))) _Float16 f16x2;
typedef __attribute__((ext_vector_type(4))) float    f32x4;

__device__ __forceinline__ float fast_sigmoid(float v) {
    return __builtin_amdgcn_rcpf(1.f + __expf(-v));
}
__device__ __forceinline__ float fast_tanh(float v) {
    return 1.f - 2.f * __builtin_amdgcn_rcpf(__expf(2.f * v) + 1.f);
}

__global__ void
__attribute__((amdgpu_flat_work_group_size(NTHR, NTHR), amdgpu_waves_per_eu(2, 2)))
gru_mfma(const float* __restrict__ x,
         const float* __restrict__ W_ih, const float* __restrict__ W_hh,
         const float* __restrict__ b_ih, const float* __restrict__ b_hh,
         const float* __restrict__ W1, const float* __restrict__ b1,
         const float* __restrict__ W2, const float* __restrict__ b2,
         float* __restrict__ out)
{
    __shared__ __align__(16) _Float16 WH[24 * 4 * 4 * 128];  // 98,304 B
    __shared__ __align__(16) _Float16 WI[24 * 2 * 4 * 128];  // 49,152 B
    __shared__ __align__(16) _Float16 U [6 * 4 * 16 * 8];    //  6,144 B

    const int tid  = threadIdx.x;
    const int w    = tid >> 6;        // wave 0..7: gate rows 16w..16w+15
    const int l    = tid & 63;
    const int q    = l >> 4;
    const int bcol = l & 15;
    const int b0   = blockIdx.x * NB;

    // ---- stage W_hh, W_ih into LDS in A-fragment layout (one-time)
    for (int i = tid; i < Gdim * Hdim; i += NTHR) {
        int gr = i >> 7, k = i & 127;
        int idx = (((gr >> 4) * 4 + (k >> 5)) * 4 + ((k & 31) >> 3)) * 128
                + (gr & 15) * 8 + (k & 7);
        WH[idx] = (_Float16)W_hh[i];
    }
    for (int i = tid; i < Gdim * Fdim; i += NTHR) {
        int gr = i >> 6, k = i & 63;
        int idx = (((gr >> 4) * 2 + (k >> 5)) * 4 + ((k & 31) >> 3)) * 128
                + (gr & 15) * 8 + (k & 7);
        WI[idx] = (_Float16)W_ih[i];
    }
    for (int i = tid; i < 2048; i += NTHR) U[i] = (_Float16)0.f;  // h = 0
    {   // stage x(t=0)
        int e = tid * 2, bx_ = e >> 6, j = e & 63;
        float2 xv = *reinterpret_cast<const float2*>(
            &x[((size_t)(b0 + bx_) * Tlen + 0) * Fdim + j]);
        int kk = 128 + j;
        int idx = (((kk >> 5) * 4 + ((kk & 31) >> 3)) * 16 + bx_) * 8 + (kk & 7);
        U[idx]     = (_Float16)xv.x;
        U[idx + 1] = (_Float16)xv.y;
    }

    // ---- per-lane biases (gate rows 16w + q*4 + j)
    float br[4], bz[4], bnh[4], bnx[4];
    #pragma unroll
    for (int j = 0; j < 4; ++j) {
        int gr = 16 * w + q * 4 + j;
        br[j]  = b_ih[gr] + b_hh[gr];
        bz[j]  = b_ih[Hdim + gr] + b_hh[Hdim + gr];
        bnh[j] = b_hh[2 * Hdim + gr];
        bnx[j] = b_ih[2 * Hdim + gr];
    }

    float hp0 = 0.f, hp1 = 0.f, hp2 = 0.f, hp3 = 0.f;

    const int kb    = 16 * w + 4 * q;
    const int hbase = (((kb >> 5) * 4 + ((kb & 31) >> 3)) * 16 + bcol) * 8 + (kb & 7);

    const int e_x = tid * 2, bx = e_x >> 6, jx = e_x & 63;
    const int kx  = 128 + jx;
    const int xidx = (((kx >> 5) * 4 + ((kx & 31) >> 3)) * 16 + bx) * 8 + (kx & 7);

    __syncthreads();

#define WHF(gt, kt) (*reinterpret_cast<const f16x8*>(&WH[((((gt)*4+(kt))*4+q)*128) + (l&15)*8]))
#define WIF(gt, kt) (*reinterpret_cast<const f16x8*>(&WI[((((gt)*2+(kt))*4+q)*128) + (l&15)*8]))
#define UF(kt)      (*reinterpret_cast<const f16x8*>(&U[(((kt)*4+q)*16 + bcol)*8]))
#define MFMA(a, b, c) __builtin_amdgcn_mfma_f32_16x16x32_f16((a), (b), (c), 0, 0, 0)

    // ---- hoist 18 weight fragments into registers, pin against sinking
    f16x8 whr0 = WHF(w, 0),      whr1 = WHF(w, 1),      whr2 = WHF(w, 2),      whr3 = WHF(w, 3);
    f16x8 whz0 = WHF(8 + w, 0),  whz1 = WHF(8 + w, 1),  whz2 = WHF(8 + w, 2),  whz3 = WHF(8 + w, 3);
    f16x8 whn0 = WHF(16 + w, 0), whn1 = WHF(16 + w, 1), whn2 = WHF(16 + w, 2), whn3 = WHF(16 + w, 3);
    f16x8 wir0 = WIF(w, 0),      wir1 = WIF(w, 1);
    f16x8 wiz0 = WIF(8 + w, 0),  wiz1 = WIF(8 + w, 1);
    f16x8 win0 = WIF(16 + w, 0), win1 = WIF(16 + w, 1);
    asm volatile("" : "+v"(whr0), "+v"(whr1), "+v"(whr2), "+v"(whr3),
                      "+v"(whz0), "+v"(whz1));
    asm volatile("" : "+v"(whz2), "+v"(whz3), "+v"(whn0), "+v"(whn1),
                      "+v"(whn2), "+v"(whn3));
    asm volatile("" : "+v"(wir0), "+v"(wir1), "+v"(wiz0), "+v"(wiz1),
                      "+v"(win0), "+v"(win1));

    // ---- x prefetch pipeline, lookahead 3: R[t&1] written to LDS at step t
    // holds x(t+1); refilled at step t with x(t+3).
    float2 xpA = {0.f, 0.f}, xpB = {0.f, 0.f};
    xpA = *reinterpret_cast<const float2*>(&x[((size_t)(b0 + bx) * Tlen + 1) * Fdim + jx]);
    xpB = *reinterpret_cast<const float2*>(&x[((size_t)(b0 + bx) * Tlen + 2) * Fdim + jx]);

    #pragma unroll 1
    for (int t = 0; t < Tlen; ++t) {
        // ---- early: u fragments (h: 4 tiles, x: 2 tiles)
        f16x8 ub0 = UF(0), ub1 = UF(1), ub2 = UF(2), ub3 = UF(3);
        f16x8 ub4 = UF(4), ub5 = UF(5);

        // ---- MFMA phase: per gate 2 chains of 3 (dep depth halved)
        f32x4 cra = {br[0], br[1], br[2], br[3]},     crb = {0.f, 0.f, 0.f, 0.f};
        f32x4 cza = {bz[0], bz[1], bz[2], bz[3]},     czb = {0.f, 0.f, 0.f, 0.f};
        f32x4 cnha = {bnh[0], bnh[1], bnh[2], bnh[3]}, cnhb = {0.f, 0.f, 0.f, 0.f};
        f32x4 cnx = {bnx[0], bnx[1], bnx[2], bnx[3]};

        cra = MFMA(whr0, ub0, cra);   crb = MFMA(whr1, ub1, crb);
        cza = MFMA(whz0, ub0, cza);   czb = MFMA(whz1, ub1, czb);
        cnha = MFMA(whn0, ub0, cnha); cnhb = MFMA(whn1, ub1, cnhb);
        cra = MFMA(whr2, ub2, cra);   crb = MFMA(whr3, ub3, crb);
        cza = MFMA(whz2, ub2, cza);   czb = MFMA(whz3, ub3, czb);
        cnha = MFMA(whn2, ub2, cnha); cnhb = MFMA(whn3, ub3, cnhb);
        cra = MFMA(wir0, ub4, cra);   crb = MFMA(wir1, ub5, crb);
        cza = MFMA(wiz0, ub4, cza);   czb = MFMA(wiz1, ub5, czb);
        cnx = MFMA(win0, ub4, cnx);   cnx = MFMA(win1, ub5, cnx);

        __syncthreads();   // A: all U reads complete

        f32x4 cr = cra + crb, cz = cza + czb, cnh = cnha + cnhb;

        float r0 = fast_sigmoid(cr[0]), z0 = fast_sigmoid(cz[0]);
        float r1 = fast_sigmoid(cr[1]), z1 = fast_sigmoid(cz[1]);
        float r2 = fast_sigmoid(cr[2]), z2 = fast_sigmoid(cz[2]);
        float r3 = fast_sigmoid(cr[3]), z3 = fast_sigmoid(cz[3]);
        float n0 = fast_tanh(cnx[0] + r0 * cnh[0]);
        float n1 = fast_tanh(cnx[1] + r1 * cnh[1]);
        float n2 = fast_tanh(cnx[2] + r2 * cnh[2]);
        float n3 = fast_tanh(cnx[3] + r3 * cnh[3]);
        hp0 = (1.f - z0) * n0 + z0 * hp0;
        hp1 = (1.f - z1) * n1 + z1 * hp1;
        hp2 = (1.f - z2) * n2 + z2 * hp2;
        hp3 = (1.f - z3) * n3 + z3 * hp3;

        f16x4 hq = {(_Float16)hp0, (_Float16)hp1, (_Float16)hp2, (_Float16)hp3};
        *reinterpret_cast<f16x4*>(&U[hbase]) = hq;

        // ---- x staging: write x(t+1) from reg; refill reg with x(t+3)
        if (t + 1 < Tlen) {
            float2 xw = (t & 1) ? xpB : xpA;
            f16x2 xq = {(_Float16)xw.x, (_Float16)xw.y};
            *reinterpret_cast<f16x2*>(&U[xidx]) = xq;
        }
        if (t + 3 < Tlen) {
            float2 xn_ = *reinterpret_cast<const float2*>(
                &x[((size_t)(b0 + bx) * Tlen + (t + 3)) * Fdim + jx]);
            if (t & 1) xpB = xn_; else xpA = xn_;
        }
        __syncthreads();   // B: U(t+1) complete
    }

    // ---- epilogue MLP: hidden = relu(hT @ W1.T + b1); out = hidden @ W2.T + b2
    {
        int m = tid & 31, b = tid >> 5;
        float acc = b1[m];
        #pragma unroll 8
        for (int k = 0; k < Hdim; ++k) {
            int ui = (((k >> 5) * 4 + ((k & 31) >> 3)) * 16 + b) * 8 + (k & 7);
            acc += W1[m * Hdim + k] * (float)U[ui];
        }
        float v = W2[m] * fmaxf(acc, 0.f);
        v += __shfl_xor(v, 1,  32);
        v += __shfl_xor(v, 2,  32);
        v += __shfl_xor(v, 4,  32);
        v += __shfl_xor(v, 8,  32);
        v += __shfl_xor(v, 16, 32);
        if (m == 0) out[b0 + b] = v + b2[0];
    }
}

extern "C" void kernel_launch(void* const* d_in, const int* in_sizes, int n_in,
                              void* d_out, int out_size, void* d_ws, size_t ws_size,
                              hipStream_t stream)
{
    const float* x    = (const float*)d_in[0];
    const float* W_ih = (const float*)d_in[1];
    const float* W_hh = (const float*)d_in[2];
    const float* b_ih = (const float*)d_in[3];
    const float* b_hh = (const float*)d_in[4];
    const float* W1   = (const float*)d_in[5];
    const float* b1   = (const float*)d_in[6];
    const float* W2   = (const float*)d_in[7];
    const float* b2   = (const float*)d_in[8];
    float* out = (float*)d_out;

    dim3 grid(NBLK), block(NTHR);
    hipLaunchKernelGGL(gru_mfma, grid, block, 0, stream,
                       x, W_ih, W_hh, b_ih, b_hh, W1, b1, W2, b2, out);
}

// Round 7
// 331.297 us; speedup vs baseline: 1.5555x; 1.5555x over previous
//
#include <hip/hip_runtime.h>
#include <math.h>

// GRUDetector: B=1024, T=512, F=64, H=128, gates (r,z,n), + MLP head (H->32->1).
// R7: R5 (425us) is LDS-BW-bound re-reading 18 weight frags/wave/step (196KB/step
// = 2310 cyc @ 85B/cyc = measured). R6's outside-loop asm pin failed (VGPR=88):
// reloading unchanged LDS is LEGAL remat, so the scheduler reloads in-loop.
// Fix: pin INSIDE the loop -> weight frags become loop-carried opaque values,
// remat impossible, must stay in VGPRs. Plus: (1) double-buffered U -> ONE
// barrier/step (Ur/Uw swap, x2 unrolled for static buffers); (2) lookahead-2
// x prefetch (xp spans a full step). Skeleton/layout/math = R5 (absmax 9.8e-4).

#define Bsz  1024
#define Tlen 512
#define Fdim 64
#define Hdim 128
#define Gdim 384
#define NB   16
#define NTHR 512
#define NBLK (Bsz / NB)   // 64

typedef __attribute__((ext_vector_type(8))) _Float16 f16x8;
typedef __attribute__((ext_vector_type(4))) _Float16 f16x4;
typedef __attribute__((ext_vector_type(2))) _Float16 f16x2;
typedef __attribute__((ext_vector_type(4))) float    f32x4;

__device__ __forceinline__ float fast_sigmoid(float v) {
    return __builtin_amdgcn_rcpf(1.f + __expf(-v));
}
__device__ __forceinline__ float fast_tanh(float v) {
    return 1.f - 2.f * __builtin_amdgcn_rcpf(__expf(2.f * v) + 1.f);
}

__global__ void
__attribute__((amdgpu_flat_work_group_size(NTHR, NTHR), amdgpu_waves_per_eu(2, 2)))
gru_mfma(const float* __restrict__ x,
         const float* __restrict__ W_ih, const float* __restrict__ W_hh,
         const float* __restrict__ b_ih, const float* __restrict__ b_hh,
         const float* __restrict__ W1, const float* __restrict__ b1,
         const float* __restrict__ W2, const float* __restrict__ b2,
         float* __restrict__ out)
{
    __shared__ __align__(16) _Float16 WH[24 * 4 * 4 * 128];  // 98,304 B
    __shared__ __align__(16) _Float16 WI[24 * 2 * 4 * 128];  // 49,152 B
    __shared__ __align__(16) _Float16 U0[6 * 4 * 16 * 8];    //  6,144 B
    __shared__ __align__(16) _Float16 U1[6 * 4 * 16 * 8];    //  6,144 B  (tot 156 KB)

    const int tid  = threadIdx.x;
    const int w    = tid >> 6;        // wave 0..7: gate rows 16w..16w+15
    const int l    = tid & 63;
    const int q    = l >> 4;
    const int bcol = l & 15;
    const int b0   = blockIdx.x * NB;

    // ---- stage W_hh, W_ih into LDS in A-fragment layout (one-time)
    for (int i = tid; i < Gdim * Hdim; i += NTHR) {
        int gr = i >> 7, k = i & 127;
        int idx = (((gr >> 4) * 4 + (k >> 5)) * 4 + ((k & 31) >> 3)) * 128
                + (gr & 15) * 8 + (k & 7);
        WH[idx] = (_Float16)W_hh[i];
    }
    for (int i = tid; i < Gdim * Fdim; i += NTHR) {
        int gr = i >> 6, k = i & 63;
        int idx = (((gr >> 4) * 2 + (k >> 5)) * 4 + ((k & 31) >> 3)) * 128
                + (gr & 15) * 8 + (k & 7);
        WI[idx] = (_Float16)W_ih[i];
    }
    for (int i = tid; i < 2048; i += NTHR) U0[i] = (_Float16)0.f;  // h(0) = 0
    {   // stage x(t=0) into U0
        int e = tid * 2, bx_ = e >> 6, j = e & 63;
        float2 xv = *reinterpret_cast<const float2*>(
            &x[((size_t)(b0 + bx_) * Tlen + 0) * Fdim + j]);
        int kk = 128 + j;
        int idx = (((kk >> 5) * 4 + ((kk & 31) >> 3)) * 16 + bx_) * 8 + (kk & 7);
        U0[idx]     = (_Float16)xv.x;
        U0[idx + 1] = (_Float16)xv.y;
    }

    // ---- per-lane biases (gate rows 16w + q*4 + j)
    float br[4], bz[4], bnh[4], bnx[4];
    #pragma unroll
    for (int j = 0; j < 4; ++j) {
        int gr = 16 * w + q * 4 + j;
        br[j]  = b_ih[gr] + b_hh[gr];
        bz[j]  = b_ih[Hdim + gr] + b_hh[Hdim + gr];
        bnh[j] = b_hh[2 * Hdim + gr];
        bnx[j] = b_ih[2 * Hdim + gr];
    }

    float hp0 = 0.f, hp1 = 0.f, hp2 = 0.f, hp3 = 0.f;

    const int kb    = 16 * w + 4 * q;
    const int hbase = (((kb >> 5) * 4 + ((kb & 31) >> 3)) * 16 + bcol) * 8 + (kb & 7);

    const int e_x = tid * 2, bx = e_x >> 6, jx = e_x & 63;
    const int kx  = 128 + jx;
    const int xidx = (((kx >> 5) * 4 + ((kx & 31) >> 3)) * 16 + bx) * 8 + (kx & 7);
    const float* xsrc = &x[(size_t)(b0 + bx) * Tlen * Fdim + jx];

    __syncthreads();

#define WHF(gt, kt) (*reinterpret_cast<const f16x8*>(&WH[((((gt)*4+(kt))*4+q)*128) + (l&15)*8]))
#define WIF(gt, kt) (*reinterpret_cast<const f16x8*>(&WI[((((gt)*2+(kt))*4+q)*128) + (l&15)*8]))
#define MFMA(a, b, c) __builtin_amdgcn_mfma_f32_16x16x32_f16((a), (b), (c), 0, 0, 0)

    // ---- load 18 weight fragments once
    f16x8 whr0 = WHF(w, 0),      whr1 = WHF(w, 1),      whr2 = WHF(w, 2),      whr3 = WHF(w, 3);
    f16x8 whz0 = WHF(8 + w, 0),  whz1 = WHF(8 + w, 1),  whz2 = WHF(8 + w, 2),  whz3 = WHF(8 + w, 3);
    f16x8 whn0 = WHF(16 + w, 0), whn1 = WHF(16 + w, 1), whn2 = WHF(16 + w, 2), whn3 = WHF(16 + w, 3);
    f16x8 wir0 = WIF(w, 0),      wir1 = WIF(w, 1);
    f16x8 wiz0 = WIF(8 + w, 0),  wiz1 = WIF(8 + w, 1);
    f16x8 win0 = WIF(16 + w, 0), win1 = WIF(16 + w, 1);

    // x prefetch: xp holds x(t+1) entering step t
    float2 xp = *reinterpret_cast<const float2*>(xsrc + (size_t)1 * Fdim);

    // ---- one GRU step: read Ur, write Uw, single barrier
    auto step = [&](const _Float16* __restrict__ Ur, _Float16* __restrict__ Uw, int t) {
        // PIN weights inside the loop: loop-carried opaque values -> no remat
        asm volatile("" : "+v"(whr0), "+v"(whr1), "+v"(whr2), "+v"(whr3),
                          "+v"(whz0), "+v"(whz1));
        asm volatile("" : "+v"(whz2), "+v"(whz3), "+v"(whn0), "+v"(whn1),
                          "+v"(whn2), "+v"(whn3));
        asm volatile("" : "+v"(wir0), "+v"(wir1), "+v"(wiz0), "+v"(wiz1),
                          "+v"(win0), "+v"(win1));

        // u fragments (h: 4 tiles, x: 2 tiles)
        f16x8 ub0 = *reinterpret_cast<const f16x8*>(&Ur[((0*4+q)*16 + bcol)*8]);
        f16x8 ub1 = *reinterpret_cast<const f16x8*>(&Ur[((1*4+q)*16 + bcol)*8]);
        f16x8 ub2 = *reinterpret_cast<const f16x8*>(&Ur[((2*4+q)*16 + bcol)*8]);
        f16x8 ub3 = *reinterpret_cast<const f16x8*>(&Ur[((3*4+q)*16 + bcol)*8]);
        f16x8 ub4 = *reinterpret_cast<const f16x8*>(&Ur[((4*4+q)*16 + bcol)*8]);
        f16x8 ub5 = *reinterpret_cast<const f16x8*>(&Ur[((5*4+q)*16 + bcol)*8]);

        float2 xw = xp;                                   // x(t+1), loaded a step ago
        if (t + 2 < Tlen)                                 // issue x(t+2) early
            xp = *reinterpret_cast<const float2*>(xsrc + (size_t)(t + 2) * Fdim);

        f32x4 cr  = {br[0],  br[1],  br[2],  br[3]};
        f32x4 cz  = {bz[0],  bz[1],  bz[2],  bz[3]};
        f32x4 cnh = {bnh[0], bnh[1], bnh[2], bnh[3]};
        f32x4 cnx = {bnx[0], bnx[1], bnx[2], bnx[3]};

        cr  = MFMA(whr0, ub0, cr);
        cz  = MFMA(whz0, ub0, cz);
        cnh = MFMA(whn0, ub0, cnh);
        cr  = MFMA(whr1, ub1, cr);
        cz  = MFMA(whz1, ub1, cz);
        cnh = MFMA(whn1, ub1, cnh);
        cr  = MFMA(whr2, ub2, cr);
        cz  = MFMA(whz2, ub2, cz);
        cnh = MFMA(whn2, ub2, cnh);
        cr  = MFMA(whr3, ub3, cr);
        cz  = MFMA(whz3, ub3, cz);
        cnh = MFMA(whn3, ub3, cnh);
        cr  = MFMA(wir0, ub4, cr);
        cz  = MFMA(wiz0, ub4, cz);
        cnx = MFMA(win0, ub4, cnx);
        cr  = MFMA(wir1, ub5, cr);
        cz  = MFMA(wiz1, ub5, cz);
        cnx = MFMA(win1, ub5, cnx);

        float r0 = fast_sigmoid(cr[0]), z0 = fast_sigmoid(cz[0]);
        float r1 = fast_sigmoid(cr[1]), z1 = fast_sigmoid(cz[1]);
        float r2 = fast_sigmoid(cr[2]), z2 = fast_sigmoid(cz[2]);
        float r3 = fast_sigmoid(cr[3]), z3 = fast_sigmoid(cz[3]);
        float n0 = fast_tanh(cnx[0] + r0 * cnh[0]);
        float n1 = fast_tanh(cnx[1] + r1 * cnh[1]);
        float n2 = fast_tanh(cnx[2] + r2 * cnh[2]);
        float n3 = fast_tanh(cnx[3] + r3 * cnh[3]);
        hp0 = (1.f - z0) * n0 + z0 * hp0;
        hp1 = (1.f - z1) * n1 + z1 * hp1;
        hp2 = (1.f - z2) * n2 + z2 * hp2;
        hp3 = (1.f - z3) * n3 + z3 * hp3;

        f16x4 hq = {(_Float16)hp0, (_Float16)hp1, (_Float16)hp2, (_Float16)hp3};
        *reinterpret_cast<f16x4*>(&Uw[hbase]) = hq;

        if (t + 1 < Tlen) {
            f16x2 xq = {(_Float16)xw.x, (_Float16)xw.y};
            *reinterpret_cast<f16x2*>(&Uw[xidx]) = xq;
        }
        __syncthreads();   // single barrier: Uw complete, Ur reads done
    };

    #pragma unroll 1
    for (int t = 0; t < Tlen; t += 2) {
        step(U0, U1, t);
        step(U1, U0, t + 1);
    }
    // final h(T) is in U0 (written at t = 511)

    // ---- epilogue MLP: hidden = relu(hT @ W1.T + b1); out = hidden @ W2.T + b2
    {
        int m = tid & 31, b = tid >> 5;
        float acc = b1[m];
        #pragma unroll 8
        for (int k = 0; k < Hdim; ++k) {
            int ui = (((k >> 5) * 4 + ((k & 31) >> 3)) * 16 + b) * 8 + (k & 7);
            acc += W1[m * Hdim + k] * (float)U0[ui];
        }
        float v = W2[m] * fmaxf(acc, 0.f);
        v += __shfl_xor(v, 1,  32);
        v += __shfl_xor(v, 2,  32);
        v += __shfl_xor(v, 4,  32);
        v += __shfl_xor(v, 8,  32);
        v += __shfl_xor(v, 16, 32);
        if (m == 0) out[b0 + b] = v + b2[0];
    }
}

extern "C" void kernel_launch(void* const* d_in, const int* in_sizes, int n_in,
                              void* d_out, int out_size, void* d_ws, size_t ws_size,
                              hipStream_t stream)
{
    const float* x    = (const float*)d_in[0];
    const float* W_ih = (const float*)d_in[1];
    const float* W_hh = (const float*)d_in[2];
    const float* b_ih = (const float*)d_in[3];
    const float* b_hh = (const float*)d_in[4];
    const float* W1   = (const float*)d_in[5];
    const float* b1   = (const float*)d_in[6];
    const float* W2   = (const float*)d_in[7];
    const float* b2   = (const float*)d_in[8];
    float* out = (float*)d_out;

    dim3 grid(NBLK), block(NTHR);
    hipLaunchKernelGGL(gru_mfma, grid, block, 0, stream,
                       x, W_ih, W_hh, b_ih, b_hh, W1, b1, W2, b2, out);
}